// Round 1
// baseline (2899.971 us; speedup 1.0000x reference)
//
#include <hip/hip_runtime.h>

#define NB 16
#define NA 261888
#define PRE 6000
#define POST 1000
#define CAP 16384
#define NWORDS 188   // ceil(6000/32) = 187.5 -> 188

typedef unsigned int u32;
typedef unsigned long long u64;

// ---------------- anchors (match numpy float64 -> float32 exactly) -------------
__device__ inline void anchor_at(int idx, float& a0, float& a1, float& a2, float& a3) {
    int base, fw, stride, scale;
    if (idx < 196608)      { base = 0;      fw = 256; stride = 4;  scale = 4; }
    else if (idx < 245760) { base = 196608; fw = 128; stride = 8;  scale = 8; }
    else if (idx < 258048) { base = 245760; fw = 64;  stride = 16; scale = 16; }
    else if (idx < 261120) { base = 258048; fw = 32;  stride = 32; scale = 32; }
    else                   { base = 261120; fw = 16;  stride = 64; scale = 64; }
    int rel  = idx - base;
    int ri   = rel % 3;
    int cell = rel / 3;
    int col  = cell & (fw - 1);
    int row  = cell / fw;
    double cx = (col + 0.5) * (double)stride;
    double cy = (row + 0.5) * (double)stride;
    double sz = (double)scale * 8.0;
    double sq = (ri == 0) ? 0.7071067811865476 : ((ri == 1) ? 1.0 : 1.4142135623730951);
    double wsd = sz * sq;
    double hsd = sz / sq;
    a0 = (float)(cx - 0.5 * wsd);
    a1 = (float)(cy - 0.5 * hsd);
    a2 = (float)(cx + 0.5 * wsd);
    a3 = (float)(cy + 0.5 * hsd);
}

// ---------------- K1: histogram of score bits (top 16) -------------------------
__global__ void hist_kernel(const float* __restrict__ probs, u32* __restrict__ hist) {
    int a = blockIdx.x * 256 + threadIdx.x;
    int b = blockIdx.y;
    if (a >= NA) return;
    float s = probs[((size_t)b * NA + a) * 2 + 1];
    u32 bits = __float_as_uint(s);
    atomicAdd(&hist[(size_t)b * 65536 + (bits >> 16)], 1u);
}

// ---------------- K2: per-batch threshold via suffix scan ----------------------
__global__ __launch_bounds__(1024) void thresh_kernel(const u32* __restrict__ hist, u32* __restrict__ thr) {
    __shared__ u32 csum[1024];
    int b = blockIdx.x;
    int t = threadIdx.x;
    const u32* h = hist + (size_t)b * 65536;
    u32 s = 0;
    for (int k = 0; k < 64; k++) s += h[t * 64 + k];
    csum[t] = s;
    __syncthreads();
    if (t == 0) {
        u32 cum = 0;
        int bucket = 0;
        for (int c = 1023; c >= 0; c--) {
            if (cum + csum[c] >= (u32)PRE) {
                u32 cum2 = cum;
                for (int k = 63; k >= 0; k--) {
                    cum2 += h[c * 64 + k];
                    if (cum2 >= (u32)PRE) { bucket = c * 64 + k; break; }
                }
                break;
            }
            cum += csum[c];
        }
        thr[b] = (u32)bucket << 16;
    }
}

// ---------------- K3: compact candidate keys -----------------------------------
__global__ void compact_kernel(const float* __restrict__ probs, const u32* __restrict__ thr,
                               u32* __restrict__ cnt, u64* __restrict__ cand) {
    int a = blockIdx.x * 256 + threadIdx.x;
    int b = blockIdx.y;
    if (a >= NA) return;
    float s = probs[((size_t)b * NA + a) * 2 + 1];
    u32 bits = __float_as_uint(s);
    if (bits >= thr[b]) {
        u32 pos = atomicAdd(&cnt[b], 1u);
        if (pos < CAP)
            cand[(size_t)b * CAP + pos] = ((u64)bits << 32) | (u32)(~(u32)a);
    }
}

// ---------------- K4: sort + decode + NMS + output -----------------------------
__global__ __launch_bounds__(1024) void final_kernel(const u64* __restrict__ cand, const u32* __restrict__ cnt,
                             const float* __restrict__ deltas, const float* __restrict__ img_info,
                             float* __restrict__ out) {
    __shared__ union {
        u64 keys[CAP];                    // 131072 B
        struct {
            float boxes[PRE][4];          // 96000 B
            float areas[PRE];             // 24000 B
            u32   alive[192];             // 768 B
        } n;
    } sh;
    __shared__ int s_next;

    int b = blockIdx.x;
    int tid = threadIdx.x;

    // prefill output: col0 = batch idx, boxes zero
    for (int s = tid; s < POST; s += 1024) {
        float* o = out + ((size_t)b * POST + s) * 5;
        o[0] = (float)b; o[1] = 0.f; o[2] = 0.f; o[3] = 0.f; o[4] = 0.f;
    }

    int n = (int)min(cnt[b], (u32)CAP);
    for (int i = tid; i < CAP; i += 1024)
        sh.keys[i] = (i < n) ? cand[(size_t)b * CAP + i] : 0ULL;
    __syncthreads();

    // bitonic sort, descending
    for (int k = 2; k <= CAP; k <<= 1) {
        for (int j = k >> 1; j > 0; j >>= 1) {
            for (int i = tid; i < CAP; i += 1024) {
                int ixj = i ^ j;
                if (ixj > i) {
                    u64 x = sh.keys[i], y = sh.keys[ixj];
                    bool desc = ((i & k) == 0);
                    if (desc ? (x < y) : (x > y)) { sh.keys[i] = y; sh.keys[ixj] = x; }
                }
            }
            __syncthreads();
        }
    }

    // stage top-PRE anchor indices into registers (keys region gets overwritten)
    u32 myIdx[6];
    #pragma unroll
    for (int r = 0; r < 6; r++) {
        int i = tid + r * 1024;
        if (i < PRE) myIdx[r] = ~(u32)(sh.keys[i]);
    }
    __syncthreads();

    float hmax = __fsub_rn(img_info[b * 3 + 0], 1.0f);
    float wmax = __fsub_rn(img_info[b * 3 + 1], 1.0f);

    #pragma unroll
    for (int r = 0; r < 6; r++) {
        int i = tid + r * 1024;
        if (i < PRE) {
            int a = (int)myIdx[r];
            float a0, a1, a2, a3;
            anchor_at(a, a0, a1, a2, a3);
            const float4 d4 = *(const float4*)(deltas + ((size_t)b * NA + a) * 4);
            float w  = __fadd_rn(__fsub_rn(a2, a0), 1.0f);
            float h  = __fadd_rn(__fsub_rn(a3, a1), 1.0f);
            float cx = __fadd_rn(a0, __fmul_rn(0.5f, w));
            float cy = __fadd_rn(a1, __fmul_rn(0.5f, h));
            float pcx = __fadd_rn(__fmul_rn(d4.x, w), cx);
            float pcy = __fadd_rn(__fmul_rn(d4.y, h), cy);
            float pw  = __fmul_rn((float)exp((double)d4.z), w);
            float ph  = __fmul_rn((float)exp((double)d4.w), h);
            float x1 = __fsub_rn(pcx, __fmul_rn(0.5f, pw));
            float y1 = __fsub_rn(pcy, __fmul_rn(0.5f, ph));
            float x2 = __fadd_rn(pcx, __fmul_rn(0.5f, pw));
            float y2 = __fadd_rn(pcy, __fmul_rn(0.5f, ph));
            x1 = fminf(fmaxf(x1, 0.f), wmax);
            x2 = fminf(fmaxf(x2, 0.f), wmax);
            y1 = fminf(fmaxf(y1, 0.f), hmax);
            y2 = fminf(fmaxf(y2, 0.f), hmax);
            sh.n.boxes[i][0] = x1; sh.n.boxes[i][1] = y1;
            sh.n.boxes[i][2] = x2; sh.n.boxes[i][3] = y2;
            sh.n.areas[i] = __fmul_rn(__fadd_rn(__fsub_rn(x2, x1), 1.0f),
                                      __fadd_rn(__fsub_rn(y2, y1), 1.0f));
        }
    }

    // init alive bitmask (6000 bits)
    for (int wdi = tid; wdi < 192; wdi += 1024) {
        u32 v = 0xFFFFFFFFu;
        if (wdi == 187) v = 0x0000FFFFu;
        if (wdi > 187)  v = 0u;
        sh.n.alive[wdi] = v;
    }
    __syncthreads();

    // greedy NMS, scan order
    int kept = 0;
    int scanWord = 0;  // thread-0 private, monotone
    while (kept < POST) {
        if (tid == 0) {
            int found = -1;
            while (scanWord < NWORDS) {
                u32 wv = sh.n.alive[scanWord];
                if (wv) { found = scanWord * 32 + (__ffs(wv) - 1); break; }
                scanWord++;
            }
            s_next = found;
        }
        __syncthreads();
        int i = s_next;
        if (i < 0) break;
        float bx1 = sh.n.boxes[i][0], by1 = sh.n.boxes[i][1];
        float bx2 = sh.n.boxes[i][2], by2 = sh.n.boxes[i][3];
        float bar = sh.n.areas[i];
        if (tid == 0) {
            float* o = out + ((size_t)b * POST + kept) * 5;
            o[1] = bx1; o[2] = by1; o[3] = bx2; o[4] = by2;
            atomicAnd(&sh.n.alive[i >> 5], ~(1u << (i & 31)));
        }
        for (int j = i + 1 + tid; j < PRE; j += 1024) {
            float x1 = sh.n.boxes[j][0], y1 = sh.n.boxes[j][1];
            float x2 = sh.n.boxes[j][2], y2 = sh.n.boxes[j][3];
            float xx1 = fmaxf(x1, bx1), yy1 = fmaxf(y1, by1);
            float xx2 = fminf(x2, bx2), yy2 = fminf(y2, by2);
            float iw = fmaxf(__fadd_rn(__fsub_rn(xx2, xx1), 1.0f), 0.f);
            float ih = fmaxf(__fadd_rn(__fsub_rn(yy2, yy1), 1.0f), 0.f);
            float inter = __fmul_rn(iw, ih);
            float denom = __fsub_rn(__fadd_rn(sh.n.areas[j], bar), inter);
            float iou = __fdiv_rn(inter, denom);
            if (iou > 0.7f) atomicAnd(&sh.n.alive[j >> 5], ~(1u << (j & 31)));
        }
        kept++;
        __syncthreads();
    }
}

// ---------------- launcher -----------------------------------------------------
extern "C" void kernel_launch(void* const* d_in, const int* in_sizes, int n_in,
                              void* d_out, int out_size, void* d_ws, size_t ws_size,
                              hipStream_t stream) {
    const float* probs    = (const float*)d_in[0];
    const float* deltas   = (const float*)d_in[1];
    const float* img_info = (const float*)d_in[2];
    float* out = (float*)d_out;

    char* ws = (char*)d_ws;
    const size_t HIST_BYTES = (size_t)NB * 65536 * sizeof(u32);   // 4 MiB
    u32* hist = (u32*)ws;
    u32* cnt  = (u32*)(ws + HIST_BYTES);                          // 64 B
    u32* thr  = (u32*)(ws + HIST_BYTES + 64);                     // 64 B
    u64* cand = (u64*)(ws + HIST_BYTES + 128);                    // 2 MiB

    hipMemsetAsync(ws, 0, HIST_BYTES + 64, stream);

    dim3 g1((NA + 255) / 256, NB);
    hist_kernel<<<g1, 256, 0, stream>>>(probs, hist);
    thresh_kernel<<<NB, 1024, 0, stream>>>(hist, thr);
    compact_kernel<<<g1, 256, 0, stream>>>(probs, thr, cnt, cand);
    final_kernel<<<NB, 1024, 0, stream>>>(cand, cnt, deltas, img_info, out);
}

// Round 2
// 1867.220 us; speedup vs baseline: 1.5531x; 1.5531x over previous
//
#include <hip/hip_runtime.h>

#define NB 16
#define NA 261888
#define PRE 6000
#define POST 1000
#define CAP 8192
#define NWORDS 188      // ceil(6000/32)
#define ROWW 192        // mask row width in u32 words (768 B)
#define MROWS 6016      // mask rows allocated per batch
#define BOXSTRIDE 6144  // box slots allocated per batch

typedef unsigned int u32;
typedef unsigned long long u64;

// ---------------- anchors (match numpy float64 -> float32 exactly) -------------
__device__ inline void anchor_at(int idx, float& a0, float& a1, float& a2, float& a3) {
    int base, fw, stride, scale;
    if (idx < 196608)      { base = 0;      fw = 256; stride = 4;  scale = 4; }
    else if (idx < 245760) { base = 196608; fw = 128; stride = 8;  scale = 8; }
    else if (idx < 258048) { base = 245760; fw = 64;  stride = 16; scale = 16; }
    else if (idx < 261120) { base = 258048; fw = 32;  stride = 32; scale = 32; }
    else                   { base = 261120; fw = 16;  stride = 64; scale = 64; }
    int rel  = idx - base;
    int ri   = rel % 3;
    int cell = rel / 3;
    int col  = cell & (fw - 1);
    int row  = cell / fw;
    double cx = (col + 0.5) * (double)stride;
    double cy = (row + 0.5) * (double)stride;
    double sz = (double)scale * 8.0;
    double sq = (ri == 0) ? 0.7071067811865476 : ((ri == 1) ? 1.0 : 1.4142135623730951);
    double wsd = sz * sq;
    double hsd = sz / sq;
    a0 = (float)(cx - 0.5 * wsd);
    a1 = (float)(cy - 0.5 * hsd);
    a2 = (float)(cx + 0.5 * wsd);
    a3 = (float)(cy + 0.5 * hsd);
}

// ---------------- K1: histogram of score bits (top 16) -------------------------
__global__ void hist_kernel(const float* __restrict__ probs, u32* __restrict__ hist) {
    int a = blockIdx.x * 256 + threadIdx.x;
    int b = blockIdx.y;
    if (a >= NA) return;
    float s = probs[((size_t)b * NA + a) * 2 + 1];
    u32 bits = __float_as_uint(s);
    atomicAdd(&hist[(size_t)b * 65536 + (bits >> 16)], 1u);
}

// ---------------- K2: per-batch threshold via suffix scan ----------------------
__global__ __launch_bounds__(1024) void thresh_kernel(const u32* __restrict__ hist, u32* __restrict__ thr) {
    __shared__ u32 csum[1024];
    int b = blockIdx.x;
    int t = threadIdx.x;
    const u32* h = hist + (size_t)b * 65536;
    u32 s = 0;
    for (int k = 0; k < 64; k++) s += h[t * 64 + k];
    csum[t] = s;
    __syncthreads();
    if (t == 0) {
        u32 cum = 0;
        int bucket = 0;
        for (int c = 1023; c >= 0; c--) {
            if (cum + csum[c] >= (u32)PRE) {
                u32 cum2 = cum;
                for (int k = 63; k >= 0; k--) {
                    cum2 += h[c * 64 + k];
                    if (cum2 >= (u32)PRE) { bucket = c * 64 + k; break; }
                }
                break;
            }
            cum += csum[c];
        }
        thr[b] = (u32)bucket << 16;
    }
}

// ---------------- K3: compact candidate keys -----------------------------------
__global__ void compact_kernel(const float* __restrict__ probs, const u32* __restrict__ thr,
                               u32* __restrict__ cnt, u64* __restrict__ cand) {
    int a = blockIdx.x * 256 + threadIdx.x;
    int b = blockIdx.y;
    if (a >= NA) return;
    float s = probs[((size_t)b * NA + a) * 2 + 1];
    u32 bits = __float_as_uint(s);
    if (bits >= thr[b]) {
        u32 pos = atomicAdd(&cnt[b], 1u);
        if (pos < CAP)
            cand[(size_t)b * CAP + pos] = ((u64)bits << 32) | (u32)(~(u32)a);
    }
}

// ---------------- K4: per-batch bitonic sort of candidate keys -----------------
__global__ __launch_bounds__(1024) void sort_kernel(u64* __restrict__ cand, const u32* __restrict__ cnt) {
    __shared__ u64 keys[CAP];
    int b = blockIdx.x, tid = threadIdx.x;
    int n = (int)min(cnt[b], (u32)CAP);
    u64* cb = cand + (size_t)b * CAP;
    for (int i = tid; i < CAP; i += 1024) keys[i] = (i < n) ? cb[i] : 0ULL;
    __syncthreads();
    for (int k = 2; k <= CAP; k <<= 1) {
        for (int j = k >> 1; j > 0; j >>= 1) {
            for (int i = tid; i < CAP; i += 1024) {
                int ixj = i ^ j;
                if (ixj > i) {
                    u64 x = keys[i], y = keys[ixj];
                    bool desc = ((i & k) == 0);
                    if (desc ? (x < y) : (x > y)) { keys[i] = y; keys[ixj] = x; }
                }
            }
            __syncthreads();
        }
    }
    for (int i = tid; i < PRE; i += 1024) cb[i] = keys[i];
}

// ---------------- K5: decode+clip top-PRE boxes; prefill output ----------------
__global__ void decode_kernel(const u64* __restrict__ cand, const float* __restrict__ deltas,
                              const float* __restrict__ img_info, float4* __restrict__ boxes,
                              float* __restrict__ out) {
    int s = blockIdx.x * 256 + threadIdx.x;
    int b = blockIdx.y;
    if (s < POST) {
        float* o = out + ((size_t)b * POST + s) * 5;
        o[0] = (float)b; o[1] = 0.f; o[2] = 0.f; o[3] = 0.f; o[4] = 0.f;
    }
    if (s >= BOXSTRIDE) return;
    if (s >= PRE) { boxes[(size_t)b * BOXSTRIDE + s] = make_float4(0.f, 0.f, 0.f, 0.f); return; }

    u64 key = cand[(size_t)b * CAP + s];
    int a = (int)(~(u32)key);
    float a0, a1, a2, a3;
    anchor_at(a, a0, a1, a2, a3);
    const float4 d4 = *(const float4*)(deltas + ((size_t)b * NA + a) * 4);
    float hmax = __fsub_rn(img_info[b * 3 + 0], 1.0f);
    float wmax = __fsub_rn(img_info[b * 3 + 1], 1.0f);
    float w  = __fadd_rn(__fsub_rn(a2, a0), 1.0f);
    float h  = __fadd_rn(__fsub_rn(a3, a1), 1.0f);
    float cx = __fadd_rn(a0, __fmul_rn(0.5f, w));
    float cy = __fadd_rn(a1, __fmul_rn(0.5f, h));
    float pcx = __fadd_rn(__fmul_rn(d4.x, w), cx);
    float pcy = __fadd_rn(__fmul_rn(d4.y, h), cy);
    float pw  = __fmul_rn((float)exp((double)d4.z), w);
    float ph  = __fmul_rn((float)exp((double)d4.w), h);
    float x1 = __fsub_rn(pcx, __fmul_rn(0.5f, pw));
    float y1 = __fsub_rn(pcy, __fmul_rn(0.5f, ph));
    float x2 = __fadd_rn(pcx, __fmul_rn(0.5f, pw));
    float y2 = __fadd_rn(pcy, __fmul_rn(0.5f, ph));
    x1 = fminf(fmaxf(x1, 0.f), wmax);
    x2 = fminf(fmaxf(x2, 0.f), wmax);
    y1 = fminf(fmaxf(y1, 0.f), hmax);
    y2 = fminf(fmaxf(y2, 0.f), hmax);
    boxes[(size_t)b * BOXSTRIDE + s] = make_float4(x1, y1, x2, y2);
}

// ---------------- K6: IoU suppression bit-mask build ---------------------------
// mask[b][i][W] bit k: IoU(box i, box 32W+k) > 0.7. Lower-triangle tiles are
// don't-care (alive bits < i are already 0 when row i is applied) and skipped.
__global__ __launch_bounds__(256) void mask_kernel(const float4* __restrict__ boxes, u32* __restrict__ mask) {
    __shared__ float4 rowbox[64];
    __shared__ float4 colbox[1024];
    int rt = blockIdx.x;          // row tile: 64 rows
    int b  = blockIdx.y;
    int t  = threadIdx.x;
    int r0tile = rt * 64;
    const float4* bb = boxes + (size_t)b * BOXSTRIDE;
    if (t < 64) rowbox[t] = bb[r0tile + t];

    int w = t & 31;
    int rgBase = t >> 5;          // 0..7
    u32* mb = mask + (size_t)b * MROWS * ROWW;

    for (int c = 0; c < 6; ++c) {
        __syncthreads();
        #pragma unroll
        for (int q = 0; q < 4; ++q) {
            int idx = t + q * 256;
            colbox[idx] = bb[c * 1024 + idx];
        }
        __syncthreads();
        int jc0 = c * 1024 + w * 32;
        int W = c * 32 + w;
        #pragma unroll
        for (int task = 0; task < 2; ++task) {
            int rg = rgBase + task * 8;
            int r0 = r0tile + rg * 4;
            if (r0 >= PRE) continue;
            if (jc0 + 32 <= r0) continue;   // strictly below diagonal: skip
            float4 rb[4]; float ra[4];
            #pragma unroll
            for (int q = 0; q < 4; ++q) {
                rb[q] = rowbox[rg * 4 + q];
                ra[q] = __fmul_rn(__fadd_rn(__fsub_rn(rb[q].z, rb[q].x), 1.0f),
                                  __fadd_rn(__fsub_rn(rb[q].w, rb[q].y), 1.0f));
            }
            u32 bits[4] = {0u, 0u, 0u, 0u};
            for (int k = 0; k < 32; ++k) {
                int j = jc0 + k;
                float4 cbx = colbox[w * 32 + k];
                float ca = __fmul_rn(__fadd_rn(__fsub_rn(cbx.z, cbx.x), 1.0f),
                                     __fadd_rn(__fsub_rn(cbx.w, cbx.y), 1.0f));
                bool okj = (j < PRE);
                #pragma unroll
                for (int q = 0; q < 4; ++q) {
                    float xx1 = fmaxf(cbx.x, rb[q].x);
                    float yy1 = fmaxf(cbx.y, rb[q].y);
                    float xx2 = fminf(cbx.z, rb[q].z);
                    float yy2 = fminf(cbx.w, rb[q].w);
                    float iw = fmaxf(__fadd_rn(__fsub_rn(xx2, xx1), 1.0f), 0.f);
                    float ih = fmaxf(__fadd_rn(__fsub_rn(yy2, yy1), 1.0f), 0.f);
                    float inter = __fmul_rn(iw, ih);
                    float denom = __fsub_rn(__fadd_rn(ca, ra[q]), inter);
                    float iou = __fdiv_rn(inter, denom);
                    if (okj && (iou > 0.7f)) bits[q] |= (1u << k);
                }
            }
            #pragma unroll
            for (int q = 0; q < 4; ++q) {
                int row = r0 + q;
                if (row < PRE) mb[(size_t)row * ROWW + W] = bits[q];
            }
        }
    }
}

// ---------------- K7: single-wave greedy NMS scan -------------------------------
__global__ __launch_bounds__(64) void scan_kernel(const u32* __restrict__ mask, const float4* __restrict__ boxes,
                            float* __restrict__ out) {
    __shared__ int keptIdx[POST];
    int b = blockIdx.x, l = threadIdx.x;
    int w0 = 3 * l;
    u32 aw0 = (w0 < 187) ? 0xFFFFFFFFu : ((w0 == 187) ? 0xFFFFu : 0u);
    u32 aw1 = (w0 + 1 < 187) ? 0xFFFFFFFFu : ((w0 + 1 == 187) ? 0xFFFFu : 0u);
    u32 aw2 = (w0 + 2 < 187) ? 0xFFFFFFFFu : ((w0 + 2 == 187) ? 0xFFFFu : 0u);
    const u32* mb = mask + (size_t)b * MROWS * ROWW;
    int kept = 0;
    while (kept < POST) {
        u32 any = aw0 | aw1 | aw2;
        u64 bal = __ballot(any != 0u);
        if (bal == 0ULL) break;
        int ll = __ffsll(bal) - 1;
        int loc;
        if (aw0)      loc = w0 * 32 + (__ffs(aw0) - 1);
        else if (aw1) loc = (w0 + 1) * 32 + (__ffs(aw1) - 1);
        else          loc = (w0 + 2) * 32 + (__ffs(aw2) - 1);
        int j = __shfl(loc, ll);
        if (l == ll) keptIdx[kept] = j;
        const u32* row = mb + (size_t)j * ROWW + w0;
        aw0 &= ~row[0];          // diagonal bit clears j itself
        aw1 &= ~row[1];
        aw2 &= ~row[2];
        ++kept;
    }
    __syncthreads();
    for (int s = l; s < kept; s += 64) {
        int j = keptIdx[s];
        float4 bx = boxes[(size_t)b * BOXSTRIDE + j];
        float* o = out + ((size_t)b * POST + s) * 5;
        o[0] = (float)b; o[1] = bx.x; o[2] = bx.y; o[3] = bx.z; o[4] = bx.w;
    }
}

// ---------------- fallback: monolithic sort+decode+NMS (small ws) ---------------
__global__ __launch_bounds__(1024) void final_kernel(const u64* __restrict__ cand, const u32* __restrict__ cnt,
                             const float* __restrict__ deltas, const float* __restrict__ img_info,
                             float* __restrict__ out) {
    __shared__ union {
        u64 keys[CAP];
        struct {
            float boxes[PRE][4];
            float areas[PRE];
            u32   alive[192];
        } n;
    } sh;
    __shared__ int s_next;

    int b = blockIdx.x;
    int tid = threadIdx.x;

    for (int s = tid; s < POST; s += 1024) {
        float* o = out + ((size_t)b * POST + s) * 5;
        o[0] = (float)b; o[1] = 0.f; o[2] = 0.f; o[3] = 0.f; o[4] = 0.f;
    }

    int n = (int)min(cnt[b], (u32)CAP);
    for (int i = tid; i < CAP; i += 1024)
        sh.keys[i] = (i < n) ? cand[(size_t)b * CAP + i] : 0ULL;
    __syncthreads();

    for (int k = 2; k <= CAP; k <<= 1) {
        for (int j = k >> 1; j > 0; j >>= 1) {
            for (int i = tid; i < CAP; i += 1024) {
                int ixj = i ^ j;
                if (ixj > i) {
                    u64 x = sh.keys[i], y = sh.keys[ixj];
                    bool desc = ((i & k) == 0);
                    if (desc ? (x < y) : (x > y)) { sh.keys[i] = y; sh.keys[ixj] = x; }
                }
            }
            __syncthreads();
        }
    }

    u32 myIdx[6];
    #pragma unroll
    for (int r = 0; r < 6; r++) {
        int i = tid + r * 1024;
        if (i < PRE) myIdx[r] = ~(u32)(sh.keys[i]);
    }
    __syncthreads();

    float hmax = __fsub_rn(img_info[b * 3 + 0], 1.0f);
    float wmax = __fsub_rn(img_info[b * 3 + 1], 1.0f);

    #pragma unroll
    for (int r = 0; r < 6; r++) {
        int i = tid + r * 1024;
        if (i < PRE) {
            int a = (int)myIdx[r];
            float a0, a1, a2, a3;
            anchor_at(a, a0, a1, a2, a3);
            const float4 d4 = *(const float4*)(deltas + ((size_t)b * NA + a) * 4);
            float w  = __fadd_rn(__fsub_rn(a2, a0), 1.0f);
            float h  = __fadd_rn(__fsub_rn(a3, a1), 1.0f);
            float cx = __fadd_rn(a0, __fmul_rn(0.5f, w));
            float cy = __fadd_rn(a1, __fmul_rn(0.5f, h));
            float pcx = __fadd_rn(__fmul_rn(d4.x, w), cx);
            float pcy = __fadd_rn(__fmul_rn(d4.y, h), cy);
            float pw  = __fmul_rn((float)exp((double)d4.z), w);
            float ph  = __fmul_rn((float)exp((double)d4.w), h);
            float x1 = __fsub_rn(pcx, __fmul_rn(0.5f, pw));
            float y1 = __fsub_rn(pcy, __fmul_rn(0.5f, ph));
            float x2 = __fadd_rn(pcx, __fmul_rn(0.5f, pw));
            float y2 = __fadd_rn(pcy, __fmul_rn(0.5f, ph));
            x1 = fminf(fmaxf(x1, 0.f), wmax);
            x2 = fminf(fmaxf(x2, 0.f), wmax);
            y1 = fminf(fmaxf(y1, 0.f), hmax);
            y2 = fminf(fmaxf(y2, 0.f), hmax);
            sh.n.boxes[i][0] = x1; sh.n.boxes[i][1] = y1;
            sh.n.boxes[i][2] = x2; sh.n.boxes[i][3] = y2;
            sh.n.areas[i] = __fmul_rn(__fadd_rn(__fsub_rn(x2, x1), 1.0f),
                                      __fadd_rn(__fsub_rn(y2, y1), 1.0f));
        }
    }

    for (int wdi = tid; wdi < 192; wdi += 1024) {
        u32 v = 0xFFFFFFFFu;
        if (wdi == 187) v = 0x0000FFFFu;
        if (wdi > 187)  v = 0u;
        sh.n.alive[wdi] = v;
    }
    __syncthreads();

    int kept = 0;
    int scanWord = 0;
    while (kept < POST) {
        if (tid == 0) {
            int found = -1;
            while (scanWord < NWORDS) {
                u32 wv = sh.n.alive[scanWord];
                if (wv) { found = scanWord * 32 + (__ffs(wv) - 1); break; }
                scanWord++;
            }
            s_next = found;
        }
        __syncthreads();
        int i = s_next;
        if (i < 0) break;
        float bx1 = sh.n.boxes[i][0], by1 = sh.n.boxes[i][1];
        float bx2 = sh.n.boxes[i][2], by2 = sh.n.boxes[i][3];
        float bar = sh.n.areas[i];
        if (tid == 0) {
            float* o = out + ((size_t)b * POST + kept) * 5;
            o[1] = bx1; o[2] = by1; o[3] = bx2; o[4] = by2;
            atomicAnd(&sh.n.alive[i >> 5], ~(1u << (i & 31)));
        }
        for (int j = i + 1 + tid; j < PRE; j += 1024) {
            float x1 = sh.n.boxes[j][0], y1 = sh.n.boxes[j][1];
            float x2 = sh.n.boxes[j][2], y2 = sh.n.boxes[j][3];
            float xx1 = fmaxf(x1, bx1), yy1 = fmaxf(y1, by1);
            float xx2 = fminf(x2, bx2), yy2 = fminf(y2, by2);
            float iw = fmaxf(__fadd_rn(__fsub_rn(xx2, xx1), 1.0f), 0.f);
            float ih = fmaxf(__fadd_rn(__fsub_rn(yy2, yy1), 1.0f), 0.f);
            float inter = __fmul_rn(iw, ih);
            float denom = __fsub_rn(__fadd_rn(sh.n.areas[j], bar), inter);
            float iou = __fdiv_rn(inter, denom);
            if (iou > 0.7f) atomicAnd(&sh.n.alive[j >> 5], ~(1u << (j & 31)));
        }
        kept++;
        __syncthreads();
    }
}

// ---------------- launcher -----------------------------------------------------
extern "C" void kernel_launch(void* const* d_in, const int* in_sizes, int n_in,
                              void* d_out, int out_size, void* d_ws, size_t ws_size,
                              hipStream_t stream) {
    const float* probs    = (const float*)d_in[0];
    const float* deltas   = (const float*)d_in[1];
    const float* img_info = (const float*)d_in[2];
    float* out = (float*)d_out;

    char* ws = (char*)d_ws;
    size_t off = 0;
    u32* hist = (u32*)(ws + off); off += (size_t)NB * 65536 * sizeof(u32);   // 4 MiB
    u32* cnt  = (u32*)(ws + off); off += 256;
    u32* thr  = (u32*)(ws + off); off += 256;
    u64* cand = (u64*)(ws + off); off += (size_t)NB * CAP * sizeof(u64);     // 1 MiB
    float4* boxes = (float4*)(ws + off); off += (size_t)NB * BOXSTRIDE * sizeof(float4); // 1.5 MiB
    u32* mask = (u32*)(ws + off); off += (size_t)NB * MROWS * ROWW * sizeof(u32);        // 73.9 MiB
    bool bigws = (ws_size >= off);

    hipMemsetAsync(ws, 0, (size_t)NB * 65536 * sizeof(u32) + 512, stream);

    dim3 g1((NA + 255) / 256, NB);
    hist_kernel<<<g1, 256, 0, stream>>>(probs, hist);
    thresh_kernel<<<NB, 1024, 0, stream>>>(hist, thr);
    compact_kernel<<<g1, 256, 0, stream>>>(probs, thr, cnt, cand);

    if (bigws) {
        sort_kernel<<<NB, 1024, 0, stream>>>(cand, cnt);
        decode_kernel<<<dim3(BOXSTRIDE / 256, NB), 256, 0, stream>>>(cand, deltas, img_info, boxes, out);
        mask_kernel<<<dim3(94, NB), 256, 0, stream>>>(boxes, mask);
        scan_kernel<<<NB, 64, 0, stream>>>(mask, boxes, out);
    } else {
        final_kernel<<<NB, 1024, 0, stream>>>(cand, cnt, deltas, img_info, out);
    }
}

// Round 3
// 656.031 us; speedup vs baseline: 4.4205x; 2.8462x over previous
//
#include <hip/hip_runtime.h>

#define NB 16
#define NA 261888
#define PRE 6000
#define POST 1000
#define CAP 8192
#define ROWW 192        // mask row width in u32 words (768 B)
#define MROWS 6016      // mask rows allocated per batch
#define BOXSTRIDE 6144  // box slots allocated per batch
#define THRF 0.972f     // fixed fast-path threshold; E[cnt]=7333, 15.8 sigma > PRE, 10.2 sigma < CAP

typedef unsigned int u32;
typedef unsigned long long u64;

// ---------------- anchors (match numpy float64 -> float32 exactly) -------------
__device__ inline void anchor_at(int idx, float& a0, float& a1, float& a2, float& a3) {
    int base, fw, stride, scale;
    if (idx < 196608)      { base = 0;      fw = 256; stride = 4;  scale = 4; }
    else if (idx < 245760) { base = 196608; fw = 128; stride = 8;  scale = 8; }
    else if (idx < 258048) { base = 245760; fw = 64;  stride = 16; scale = 16; }
    else if (idx < 261120) { base = 258048; fw = 32;  stride = 32; scale = 32; }
    else                   { base = 261120; fw = 16;  stride = 64; scale = 64; }
    int rel  = idx - base;
    int ri   = rel % 3;
    int cell = rel / 3;
    int col  = cell & (fw - 1);
    int row  = cell / fw;
    double cx = (col + 0.5) * (double)stride;
    double cy = (row + 0.5) * (double)stride;
    double sz = (double)scale * 8.0;
    double sq = (ri == 0) ? 0.7071067811865476 : ((ri == 1) ? 1.0 : 1.4142135623730951);
    double wsd = sz * sq;
    double hsd = sz / sq;
    a0 = (float)(cx - 0.5 * wsd);
    a1 = (float)(cy - 0.5 * hsd);
    a2 = (float)(cx + 0.5 * wsd);
    a3 = (float)(cy + 0.5 * hsd);
}

// ---------------- fast path: fixed-threshold compact, block-aggregated ---------
__global__ void compact_fixed(const float* __restrict__ probs, u32* __restrict__ cntp,
                              u64* __restrict__ cand) {
    __shared__ u32 lcnt;
    __shared__ u32 lbase;
    int tid = threadIdx.x;
    int a = blockIdx.x * 256 + tid;          // NA == 1023*256, no tail
    int b = blockIdx.y;
    if (tid == 0) lcnt = 0;
    __syncthreads();
    float s = probs[((size_t)b * NA + a) * 2 + 1];
    u32 bits = __float_as_uint(s);
    int lpos = -1;
    if (s >= THRF) lpos = (int)atomicAdd(&lcnt, 1u);
    __syncthreads();
    if (tid == 0) lbase = lcnt ? atomicAdd(&cntp[b * 64], lcnt) : 0u;
    __syncthreads();
    if (lpos >= 0) {
        u32 pos = lbase + (u32)lpos;
        if (pos < CAP)
            cand[(size_t)b * CAP + pos] = ((u64)bits << 32) | (u32)(~(u32)a);
    }
}

// ---------------- validate fast path; set per-batch fallback flags -------------
__global__ void check_kernel(u32* __restrict__ cntp, u32* __restrict__ flag) {
    int t = threadIdx.x;
    if (t < NB) {
        u32 c = cntp[t * 64];
        u32 bad = (c < (u32)PRE || c > (u32)CAP) ? 1u : 0u;
        flag[t * 64] = bad;
        if (bad) cntp[t * 64] = 0;   // fallback compact restarts from 0
    }
}

// ---------------- gated fallback: zero hist ------------------------------------
__global__ void zero_hist(const u32* __restrict__ flag, u32* __restrict__ hist) {
    int b = blockIdx.y;
    if (flag[b * 64] == 0) return;
    int i = blockIdx.x * 256 + threadIdx.x;
    hist[(size_t)b * 65536 + i] = 0;
}

// ---------------- gated fallback: histogram of score bits (top 16) -------------
__global__ void hist_kernel(const u32* __restrict__ flag, const float* __restrict__ probs,
                            u32* __restrict__ hist) {
    int b = blockIdx.y;
    if (flag[b * 64] == 0) return;
    int a = blockIdx.x * 256 + threadIdx.x;
    float s = probs[((size_t)b * NA + a) * 2 + 1];
    u32 bits = __float_as_uint(s);
    atomicAdd(&hist[(size_t)b * 65536 + (bits >> 16)], 1u);
}

// ---------------- gated fallback: per-batch threshold --------------------------
__global__ __launch_bounds__(1024) void thresh_kernel(const u32* __restrict__ flag,
                                                      const u32* __restrict__ hist,
                                                      u32* __restrict__ thr) {
    int b = blockIdx.x;
    if (flag[b * 64] == 0) return;
    __shared__ u32 csum[1024];
    int t = threadIdx.x;
    const u32* h = hist + (size_t)b * 65536;
    u32 s = 0;
    for (int k = 0; k < 64; k++) s += h[t * 64 + k];
    csum[t] = s;
    __syncthreads();
    if (t == 0) {
        u32 cum = 0;
        int bucket = 0;
        for (int c = 1023; c >= 0; c--) {
            if (cum + csum[c] >= (u32)PRE) {
                u32 cum2 = cum;
                for (int k = 63; k >= 0; k--) {
                    cum2 += h[c * 64 + k];
                    if (cum2 >= (u32)PRE) { bucket = c * 64 + k; break; }
                }
                break;
            }
            cum += csum[c];
        }
        thr[b] = (u32)bucket << 16;
    }
}

// ---------------- gated fallback: compact with exact threshold -----------------
__global__ void compact2_kernel(const u32* __restrict__ flag, const float* __restrict__ probs,
                                const u32* __restrict__ thr, u32* __restrict__ cntp,
                                u64* __restrict__ cand) {
    int b = blockIdx.y;
    if (flag[b * 64] == 0) return;
    __shared__ u32 lcnt;
    __shared__ u32 lbase;
    int tid = threadIdx.x;
    int a = blockIdx.x * 256 + tid;
    if (tid == 0) lcnt = 0;
    __syncthreads();
    float s = probs[((size_t)b * NA + a) * 2 + 1];
    u32 bits = __float_as_uint(s);
    int lpos = -1;
    if (bits >= thr[b]) lpos = (int)atomicAdd(&lcnt, 1u);
    __syncthreads();
    if (tid == 0) lbase = lcnt ? atomicAdd(&cntp[b * 64], lcnt) : 0u;
    __syncthreads();
    if (lpos >= 0) {
        u32 pos = lbase + (u32)lpos;
        if (pos < CAP)
            cand[(size_t)b * CAP + pos] = ((u64)bits << 32) | (u32)(~(u32)a);
    }
}

// ---------------- per-batch bitonic sort of candidate keys ---------------------
__global__ __launch_bounds__(1024) void sort_kernel(u64* __restrict__ cand, const u32* __restrict__ cntp) {
    __shared__ u64 keys[CAP];
    int b = blockIdx.x, tid = threadIdx.x;
    int n = (int)min(cntp[b * 64], (u32)CAP);
    u64* cb = cand + (size_t)b * CAP;
    for (int i = tid; i < CAP; i += 1024) keys[i] = (i < n) ? cb[i] : 0ULL;
    __syncthreads();
    for (int k = 2; k <= CAP; k <<= 1) {
        for (int j = k >> 1; j > 0; j >>= 1) {
            for (int i = tid; i < CAP; i += 1024) {
                int ixj = i ^ j;
                if (ixj > i) {
                    u64 x = keys[i], y = keys[ixj];
                    bool desc = ((i & k) == 0);
                    if (desc ? (x < y) : (x > y)) { keys[i] = y; keys[ixj] = x; }
                }
            }
            __syncthreads();
        }
    }
    for (int i = tid; i < PRE; i += 1024) cb[i] = keys[i];
}

// ---------------- decode+clip top-PRE boxes; prefill output --------------------
__global__ void decode_kernel(const u64* __restrict__ cand, const float* __restrict__ deltas,
                              const float* __restrict__ img_info, float4* __restrict__ boxes,
                              float* __restrict__ out) {
    int s = blockIdx.x * 256 + threadIdx.x;
    int b = blockIdx.y;
    if (s < POST) {
        float* o = out + ((size_t)b * POST + s) * 5;
        o[0] = (float)b; o[1] = 0.f; o[2] = 0.f; o[3] = 0.f; o[4] = 0.f;
    }
    if (s >= BOXSTRIDE) return;
    if (s >= PRE) { boxes[(size_t)b * BOXSTRIDE + s] = make_float4(0.f, 0.f, 0.f, 0.f); return; }

    u64 key = cand[(size_t)b * CAP + s];
    int a = (int)(~(u32)key);
    float a0, a1, a2, a3;
    anchor_at(a, a0, a1, a2, a3);
    const float4 d4 = *(const float4*)(deltas + ((size_t)b * NA + a) * 4);
    float hmax = __fsub_rn(img_info[b * 3 + 0], 1.0f);
    float wmax = __fsub_rn(img_info[b * 3 + 1], 1.0f);
    float w  = __fadd_rn(__fsub_rn(a2, a0), 1.0f);
    float h  = __fadd_rn(__fsub_rn(a3, a1), 1.0f);
    float cx = __fadd_rn(a0, __fmul_rn(0.5f, w));
    float cy = __fadd_rn(a1, __fmul_rn(0.5f, h));
    float pcx = __fadd_rn(__fmul_rn(d4.x, w), cx);
    float pcy = __fadd_rn(__fmul_rn(d4.y, h), cy);
    float pw  = __fmul_rn((float)exp((double)d4.z), w);
    float ph  = __fmul_rn((float)exp((double)d4.w), h);
    float x1 = __fsub_rn(pcx, __fmul_rn(0.5f, pw));
    float y1 = __fsub_rn(pcy, __fmul_rn(0.5f, ph));
    float x2 = __fadd_rn(pcx, __fmul_rn(0.5f, pw));
    float y2 = __fadd_rn(pcy, __fmul_rn(0.5f, ph));
    x1 = fminf(fmaxf(x1, 0.f), wmax);
    x2 = fminf(fmaxf(x2, 0.f), wmax);
    y1 = fminf(fmaxf(y1, 0.f), hmax);
    y2 = fminf(fmaxf(y2, 0.f), hmax);
    boxes[(size_t)b * BOXSTRIDE + s] = make_float4(x1, y1, x2, y2);
}

// ---------------- IoU suppression bit-mask build -------------------------------
// mask[b][i][W] bit k: IoU(box i, box 32W+k) > 0.7. Tiles strictly below the
// diagonal are skipped (scan never consumes words W < i>>5).
__global__ __launch_bounds__(256) void mask_kernel(const float4* __restrict__ boxes, u32* __restrict__ mask) {
    __shared__ float4 rowbox[64];
    __shared__ float4 colbox[1024];
    int rt = blockIdx.x;          // row tile: 64 rows
    int b  = blockIdx.y;
    int t  = threadIdx.x;
    int r0tile = rt * 64;
    const float4* bb = boxes + (size_t)b * BOXSTRIDE;
    if (t < 64) rowbox[t] = bb[r0tile + t];

    int w = t & 31;
    int rgBase = t >> 5;          // 0..7
    u32* mb = mask + (size_t)b * MROWS * ROWW;

    for (int c = 0; c < 6; ++c) {
        __syncthreads();
        #pragma unroll
        for (int q = 0; q < 4; ++q) {
            int idx = t + q * 256;
            colbox[idx] = bb[c * 1024 + idx];
        }
        __syncthreads();
        int jc0 = c * 1024 + w * 32;
        int W = c * 32 + w;
        #pragma unroll
        for (int task = 0; task < 2; ++task) {
            int rg = rgBase + task * 8;
            int r0 = r0tile + rg * 4;
            if (r0 >= PRE) continue;
            if (jc0 + 32 <= r0) continue;   // strictly below diagonal: skip
            float4 rb[4]; float ra[4];
            #pragma unroll
            for (int q = 0; q < 4; ++q) {
                rb[q] = rowbox[rg * 4 + q];
                ra[q] = __fmul_rn(__fadd_rn(__fsub_rn(rb[q].z, rb[q].x), 1.0f),
                                  __fadd_rn(__fsub_rn(rb[q].w, rb[q].y), 1.0f));
            }
            u32 bits[4] = {0u, 0u, 0u, 0u};
            for (int k = 0; k < 32; ++k) {
                int j = jc0 + k;
                float4 cbx = colbox[w * 32 + k];
                float ca = __fmul_rn(__fadd_rn(__fsub_rn(cbx.z, cbx.x), 1.0f),
                                     __fadd_rn(__fsub_rn(cbx.w, cbx.y), 1.0f));
                bool okj = (j < PRE);
                #pragma unroll
                for (int q = 0; q < 4; ++q) {
                    float xx1 = fmaxf(cbx.x, rb[q].x);
                    float yy1 = fmaxf(cbx.y, rb[q].y);
                    float xx2 = fminf(cbx.z, rb[q].z);
                    float yy2 = fminf(cbx.w, rb[q].w);
                    float iw = fmaxf(__fadd_rn(__fsub_rn(xx2, xx1), 1.0f), 0.f);
                    float ih = fmaxf(__fadd_rn(__fsub_rn(yy2, yy1), 1.0f), 0.f);
                    float inter = __fmul_rn(iw, ih);
                    float denom = __fsub_rn(__fadd_rn(ca, ra[q]), inter);
                    float iou = __fdiv_rn(inter, denom);
                    if (okj && (iou > 0.7f)) bits[q] |= (1u << k);
                }
            }
            #pragma unroll
            for (int q = 0; q < 4; ++q) {
                int row = r0 + q;
                if (row < PRE) mb[(size_t)row * ROWW + W] = bits[q];
            }
        }
    }
}

// ---------------- streaming greedy NMS scan (one wave per batch) ---------------
// Iterates rows in index order with unconditional, statically-addressed loads
// (16-deep prefetch ring -> 16 outstanding), tests aliveness via __ballot.
__global__ __launch_bounds__(64) void scan_kernel(const u32* __restrict__ mask,
                                                  const float4* __restrict__ boxes,
                                                  float* __restrict__ out) {
    __shared__ int keepIdx[POST];
    int b = blockIdx.x, l = threadIdx.x;
    int w0 = 3 * l;
    u32 aw0 = (w0     < 187) ? 0xFFFFFFFFu : ((w0     == 187) ? 0xFFFFu : 0u);
    u32 aw1 = (w0 + 1 < 187) ? 0xFFFFFFFFu : ((w0 + 1 == 187) ? 0xFFFFu : 0u);
    u32 aw2 = (w0 + 2 < 187) ? 0xFFFFFFFFu : ((w0 + 2 == 187) ? 0xFFFFu : 0u);
    const u32* mb = mask + (size_t)b * MROWS * ROWW + w0;

    u32 pf[16][3];
    #pragma unroll
    for (int u = 0; u < 16; ++u) {
        const u32* r = mb + (size_t)u * ROWW;
        pf[u][0] = r[0]; pf[u][1] = r[1]; pf[u][2] = r[2];
    }

    int kept = 0;
    for (int ib = 0; ib < PRE; ib += 16) {
        #pragma unroll
        for (int u = 0; u < 16; ++u) {
            int i = ib + u;
            int w = i >> 5;
            int bit = i & 31;
            int ol = w / 3;
            int q  = w - 3 * ol;
            u32 myw = (q == 0) ? aw0 : ((q == 1) ? aw1 : aw2);
            bool pred = (l == ol) && ((myw >> bit) & 1u);
            u32 r0 = pf[u][0], r1 = pf[u][1], r2 = pf[u][2];
            // prefetch row i+16 (addresses static; stays <= MROWS-1)
            const u32* rp = mb + (size_t)(i + 16) * ROWW;
            pf[u][0] = rp[0]; pf[u][1] = rp[1]; pf[u][2] = rp[2];
            if (__ballot(pred)) {
                if (pred) keepIdx[kept] = i;
                aw0 &= ~((w0     >= w) ? r0 : 0u);
                aw1 &= ~((w0 + 1 >= w) ? r1 : 0u);
                aw2 &= ~((w0 + 2 >= w) ? r2 : 0u);
                ++kept;
                if (kept == POST) goto scan_done;
            }
        }
    }
scan_done:
    __syncthreads();
    for (int s = l; s < kept; s += 64) {
        int j = keepIdx[s];
        float4 bx = boxes[(size_t)b * BOXSTRIDE + j];
        float* o = out + ((size_t)b * POST + s) * 5;
        o[0] = (float)b; o[1] = bx.x; o[2] = bx.y; o[3] = bx.z; o[4] = bx.w;
    }
}

// ---------------- fallback: monolithic sort+decode+NMS (small ws) --------------
__global__ __launch_bounds__(1024) void final_kernel(const u64* __restrict__ cand, const u32* __restrict__ cntp,
                             const float* __restrict__ deltas, const float* __restrict__ img_info,
                             float* __restrict__ out) {
    __shared__ union {
        u64 keys[CAP];
        struct {
            float boxes[PRE][4];
            float areas[PRE];
            u32   alive[192];
        } n;
    } sh;
    __shared__ int s_next;

    int b = blockIdx.x;
    int tid = threadIdx.x;

    for (int s = tid; s < POST; s += 1024) {
        float* o = out + ((size_t)b * POST + s) * 5;
        o[0] = (float)b; o[1] = 0.f; o[2] = 0.f; o[3] = 0.f; o[4] = 0.f;
    }

    int n = (int)min(cntp[b * 64], (u32)CAP);
    for (int i = tid; i < CAP; i += 1024)
        sh.keys[i] = (i < n) ? cand[(size_t)b * CAP + i] : 0ULL;
    __syncthreads();

    for (int k = 2; k <= CAP; k <<= 1) {
        for (int j = k >> 1; j > 0; j >>= 1) {
            for (int i = tid; i < CAP; i += 1024) {
                int ixj = i ^ j;
                if (ixj > i) {
                    u64 x = sh.keys[i], y = sh.keys[ixj];
                    bool desc = ((i & k) == 0);
                    if (desc ? (x < y) : (x > y)) { sh.keys[i] = y; sh.keys[ixj] = x; }
                }
            }
            __syncthreads();
        }
    }

    u32 myIdx[6];
    #pragma unroll
    for (int r = 0; r < 6; r++) {
        int i = tid + r * 1024;
        if (i < PRE) myIdx[r] = ~(u32)(sh.keys[i]);
    }
    __syncthreads();

    float hmax = __fsub_rn(img_info[b * 3 + 0], 1.0f);
    float wmax = __fsub_rn(img_info[b * 3 + 1], 1.0f);

    #pragma unroll
    for (int r = 0; r < 6; r++) {
        int i = tid + r * 1024;
        if (i < PRE) {
            int a = (int)myIdx[r];
            float a0, a1, a2, a3;
            anchor_at(a, a0, a1, a2, a3);
            const float4 d4 = *(const float4*)(deltas + ((size_t)b * NA + a) * 4);
            float w  = __fadd_rn(__fsub_rn(a2, a0), 1.0f);
            float h  = __fadd_rn(__fsub_rn(a3, a1), 1.0f);
            float cx = __fadd_rn(a0, __fmul_rn(0.5f, w));
            float cy = __fadd_rn(a1, __fmul_rn(0.5f, h));
            float pcx = __fadd_rn(__fmul_rn(d4.x, w), cx);
            float pcy = __fadd_rn(__fmul_rn(d4.y, h), cy);
            float pw  = __fmul_rn((float)exp((double)d4.z), w);
            float ph  = __fmul_rn((float)exp((double)d4.w), h);
            float x1 = __fsub_rn(pcx, __fmul_rn(0.5f, pw));
            float y1 = __fsub_rn(pcy, __fmul_rn(0.5f, ph));
            float x2 = __fadd_rn(pcx, __fmul_rn(0.5f, pw));
            float y2 = __fadd_rn(pcy, __fmul_rn(0.5f, ph));
            x1 = fminf(fmaxf(x1, 0.f), wmax);
            x2 = fminf(fmaxf(x2, 0.f), wmax);
            y1 = fminf(fmaxf(y1, 0.f), hmax);
            y2 = fminf(fmaxf(y2, 0.f), hmax);
            sh.n.boxes[i][0] = x1; sh.n.boxes[i][1] = y1;
            sh.n.boxes[i][2] = x2; sh.n.boxes[i][3] = y2;
            sh.n.areas[i] = __fmul_rn(__fadd_rn(__fsub_rn(x2, x1), 1.0f),
                                      __fadd_rn(__fsub_rn(y2, y1), 1.0f));
        }
    }

    for (int wdi = tid; wdi < 192; wdi += 1024) {
        u32 v = 0xFFFFFFFFu;
        if (wdi == 187) v = 0x0000FFFFu;
        if (wdi > 187)  v = 0u;
        sh.n.alive[wdi] = v;
    }
    __syncthreads();

    int kept = 0;
    int scanWord = 0;
    while (kept < POST) {
        if (tid == 0) {
            int found = -1;
            while (scanWord < 188) {
                u32 wv = sh.n.alive[scanWord];
                if (wv) { found = scanWord * 32 + (__ffs(wv) - 1); break; }
                scanWord++;
            }
            s_next = found;
        }
        __syncthreads();
        int i = s_next;
        if (i < 0) break;
        float bx1 = sh.n.boxes[i][0], by1 = sh.n.boxes[i][1];
        float bx2 = sh.n.boxes[i][2], by2 = sh.n.boxes[i][3];
        float bar = sh.n.areas[i];
        if (tid == 0) {
            float* o = out + ((size_t)b * POST + kept) * 5;
            o[1] = bx1; o[2] = by1; o[3] = bx2; o[4] = by2;
            atomicAnd(&sh.n.alive[i >> 5], ~(1u << (i & 31)));
        }
        for (int j = i + 1 + tid; j < PRE; j += 1024) {
            float x1 = sh.n.boxes[j][0], y1 = sh.n.boxes[j][1];
            float x2 = sh.n.boxes[j][2], y2 = sh.n.boxes[j][3];
            float xx1 = fmaxf(x1, bx1), yy1 = fmaxf(y1, by1);
            float xx2 = fminf(x2, bx2), yy2 = fminf(y2, by2);
            float iw = fmaxf(__fadd_rn(__fsub_rn(xx2, xx1), 1.0f), 0.f);
            float ih = fmaxf(__fadd_rn(__fsub_rn(yy2, yy1), 1.0f), 0.f);
            float inter = __fmul_rn(iw, ih);
            float denom = __fsub_rn(__fadd_rn(sh.n.areas[j], bar), inter);
            float iou = __fdiv_rn(inter, denom);
            if (iou > 0.7f) atomicAnd(&sh.n.alive[j >> 5], ~(1u << (j & 31)));
        }
        kept++;
        __syncthreads();
    }
}

// ---------------- launcher -----------------------------------------------------
extern "C" void kernel_launch(void* const* d_in, const int* in_sizes, int n_in,
                              void* d_out, int out_size, void* d_ws, size_t ws_size,
                              hipStream_t stream) {
    const float* probs    = (const float*)d_in[0];
    const float* deltas   = (const float*)d_in[1];
    const float* img_info = (const float*)d_in[2];
    float* out = (float*)d_out;

    char* ws = (char*)d_ws;
    size_t off = 0;
    u32* cntp = (u32*)(ws + off); off += (size_t)NB * 64 * sizeof(u32);      // 4 KiB, 256B-strided counters
    u32* flag = (u32*)(ws + off); off += (size_t)NB * 64 * sizeof(u32);      // 4 KiB
    u32* thr  = (u32*)(ws + off); off += 4096;                                // 16 u32 (padded)
    u32* hist = (u32*)(ws + off); off += (size_t)NB * 65536 * sizeof(u32);   // 4 MiB
    u64* cand = (u64*)(ws + off); off += (size_t)NB * CAP * sizeof(u64);     // 1 MiB
    float4* boxes = (float4*)(ws + off); off += (size_t)NB * BOXSTRIDE * sizeof(float4); // 1.5 MiB
    u32* mask = (u32*)(ws + off); off += (size_t)NB * MROWS * ROWW * sizeof(u32);        // 73.9 MiB
    bool bigws = (ws_size >= off);

    dim3 gA((NA + 255) / 256, NB);

    hipMemsetAsync(cntp, 0, (size_t)NB * 64 * sizeof(u32), stream);

    if (bigws) {
        compact_fixed<<<gA, 256, 0, stream>>>(probs, cntp, cand);
        check_kernel<<<1, 64, 0, stream>>>(cntp, flag);
        // gated exact fallback (no-ops when all flags clean)
        zero_hist<<<dim3(256, NB), 256, 0, stream>>>(flag, hist);
        hist_kernel<<<gA, 256, 0, stream>>>(flag, probs, hist);
        thresh_kernel<<<NB, 1024, 0, stream>>>(flag, hist, thr);
        compact2_kernel<<<gA, 256, 0, stream>>>(flag, probs, thr, cntp, cand);
        // main pipeline
        sort_kernel<<<NB, 1024, 0, stream>>>(cand, cntp);
        decode_kernel<<<dim3(BOXSTRIDE / 256, NB), 256, 0, stream>>>(cand, deltas, img_info, boxes, out);
        mask_kernel<<<dim3(94, NB), 256, 0, stream>>>(boxes, mask);
        scan_kernel<<<NB, 64, 0, stream>>>(mask, boxes, out);
    } else {
        // small-ws: force fallback flags on, run exact path + monolithic NMS
        hipMemsetAsync(flag, 1, (size_t)NB * 64 * sizeof(u32), stream);   // nonzero == run
        hipMemsetAsync(hist, 0, (size_t)NB * 65536 * sizeof(u32), stream);
        hist_kernel<<<gA, 256, 0, stream>>>(flag, probs, hist);
        thresh_kernel<<<NB, 1024, 0, stream>>>(flag, hist, thr);
        compact2_kernel<<<gA, 256, 0, stream>>>(flag, probs, thr, cntp, cand);
        final_kernel<<<NB, 1024, 0, stream>>>(cand, cntp, deltas, img_info, out);
    }
}

// Round 4
// 566.883 us; speedup vs baseline: 5.1156x; 1.1573x over previous
//
#include <hip/hip_runtime.h>

#define NB 16
#define NA 261888
#define PRE 6000
#define POST 1000
#define CAP 8192
#define ROWW 192        // mask row width in u32 words (768 B)
#define MROWS 6016      // mask rows allocated per batch
#define BOXSTRIDE 6144  // box slots allocated per batch
#define THRF 0.972f     // fixed fast-path threshold; E[cnt]=7333, 15.8 sigma > PRE, 10.2 sigma < CAP
// Exact NMS predicate: RN32(inter/denom) > 0.7f  <=>  inter >= MBOUND * denom
// MBOUND = midpoint(0.7f, nextafterf(0.7f,inf)); 25-bit mantissa -> f64 product exact.
#define MBOUND 0x1.6666668p-1

typedef unsigned int u32;
typedef unsigned long long u64;

// ---------------- anchors (match numpy float64 -> float32 exactly) -------------
__device__ inline void anchor_at(int idx, float& a0, float& a1, float& a2, float& a3) {
    int base, fw, stride, scale;
    if (idx < 196608)      { base = 0;      fw = 256; stride = 4;  scale = 4; }
    else if (idx < 245760) { base = 196608; fw = 128; stride = 8;  scale = 8; }
    else if (idx < 258048) { base = 245760; fw = 64;  stride = 16; scale = 16; }
    else if (idx < 261120) { base = 258048; fw = 32;  stride = 32; scale = 32; }
    else                   { base = 261120; fw = 16;  stride = 64; scale = 64; }
    int rel  = idx - base;
    int ri   = rel % 3;
    int cell = rel / 3;
    int col  = cell & (fw - 1);
    int row  = cell / fw;
    double cx = (col + 0.5) * (double)stride;
    double cy = (row + 0.5) * (double)stride;
    double sz = (double)scale * 8.0;
    double sq = (ri == 0) ? 0.7071067811865476 : ((ri == 1) ? 1.0 : 1.4142135623730951);
    double wsd = sz * sq;
    double hsd = sz / sq;
    a0 = (float)(cx - 0.5 * wsd);
    a1 = (float)(cy - 0.5 * hsd);
    a2 = (float)(cx + 0.5 * wsd);
    a3 = (float)(cy + 0.5 * hsd);
}

// ---------------- fast path: fixed-threshold compact, block-aggregated ---------
__global__ void compact_fixed(const float* __restrict__ probs, u32* __restrict__ cntp,
                              u64* __restrict__ cand) {
    __shared__ u32 lcnt;
    __shared__ u32 lbase;
    int tid = threadIdx.x;
    int a = blockIdx.x * 256 + tid;          // NA == 1023*256, no tail
    int b = blockIdx.y;
    if (tid == 0) lcnt = 0;
    __syncthreads();
    float s = probs[((size_t)b * NA + a) * 2 + 1];
    u32 bits = __float_as_uint(s);
    int lpos = -1;
    if (s >= THRF) lpos = (int)atomicAdd(&lcnt, 1u);
    __syncthreads();
    if (tid == 0) lbase = lcnt ? atomicAdd(&cntp[b * 64], lcnt) : 0u;
    __syncthreads();
    if (lpos >= 0) {
        u32 pos = lbase + (u32)lpos;
        if (pos < CAP)
            cand[(size_t)b * CAP + pos] = ((u64)bits << 32) | (u32)(~(u32)a);
    }
}

// ---------------- validate fast path; set per-batch fallback flags -------------
__global__ void check_kernel(u32* __restrict__ cntp, u32* __restrict__ flag) {
    int t = threadIdx.x;
    if (t < NB) {
        u32 c = cntp[t * 64];
        u32 bad = (c < (u32)PRE || c > (u32)CAP) ? 1u : 0u;
        flag[t * 64] = bad;
        if (bad) cntp[t * 64] = 0;   // fallback compact restarts from 0
    }
}

// ---------------- gated fallback: zero hist ------------------------------------
__global__ void zero_hist(const u32* __restrict__ flag, u32* __restrict__ hist) {
    int b = blockIdx.y;
    if (flag[b * 64] == 0) return;
    int i = blockIdx.x * 256 + threadIdx.x;
    hist[(size_t)b * 65536 + i] = 0;
}

// ---------------- gated fallback: histogram of score bits (top 16) -------------
__global__ void hist_kernel(const u32* __restrict__ flag, const float* __restrict__ probs,
                            u32* __restrict__ hist) {
    int b = blockIdx.y;
    if (flag[b * 64] == 0) return;
    int a = blockIdx.x * 256 + threadIdx.x;
    float s = probs[((size_t)b * NA + a) * 2 + 1];
    u32 bits = __float_as_uint(s);
    atomicAdd(&hist[(size_t)b * 65536 + (bits >> 16)], 1u);
}

// ---------------- gated fallback: per-batch threshold --------------------------
__global__ __launch_bounds__(1024) void thresh_kernel(const u32* __restrict__ flag,
                                                      const u32* __restrict__ hist,
                                                      u32* __restrict__ thr) {
    int b = blockIdx.x;
    if (flag[b * 64] == 0) return;
    __shared__ u32 csum[1024];
    int t = threadIdx.x;
    const u32* h = hist + (size_t)b * 65536;
    u32 s = 0;
    for (int k = 0; k < 64; k++) s += h[t * 64 + k];
    csum[t] = s;
    __syncthreads();
    if (t == 0) {
        u32 cum = 0;
        int bucket = 0;
        for (int c = 1023; c >= 0; c--) {
            if (cum + csum[c] >= (u32)PRE) {
                u32 cum2 = cum;
                for (int k = 63; k >= 0; k--) {
                    cum2 += h[c * 64 + k];
                    if (cum2 >= (u32)PRE) { bucket = c * 64 + k; break; }
                }
                break;
            }
            cum += csum[c];
        }
        thr[b] = (u32)bucket << 16;
    }
}

// ---------------- gated fallback: compact with exact threshold -----------------
__global__ void compact2_kernel(const u32* __restrict__ flag, const float* __restrict__ probs,
                                const u32* __restrict__ thr, u32* __restrict__ cntp,
                                u64* __restrict__ cand) {
    int b = blockIdx.y;
    if (flag[b * 64] == 0) return;
    __shared__ u32 lcnt;
    __shared__ u32 lbase;
    int tid = threadIdx.x;
    int a = blockIdx.x * 256 + tid;
    if (tid == 0) lcnt = 0;
    __syncthreads();
    float s = probs[((size_t)b * NA + a) * 2 + 1];
    u32 bits = __float_as_uint(s);
    int lpos = -1;
    if (bits >= thr[b]) lpos = (int)atomicAdd(&lcnt, 1u);
    __syncthreads();
    if (tid == 0) lbase = lcnt ? atomicAdd(&cntp[b * 64], lcnt) : 0u;
    __syncthreads();
    if (lpos >= 0) {
        u32 pos = lbase + (u32)lpos;
        if (pos < CAP)
            cand[(size_t)b * CAP + pos] = ((u64)bits << 32) | (u32)(~(u32)a);
    }
}

// ---------------- per-batch bitonic sort of candidate keys ---------------------
__global__ __launch_bounds__(1024) void sort_kernel(u64* __restrict__ cand, const u32* __restrict__ cntp) {
    __shared__ u64 keys[CAP];
    int b = blockIdx.x, tid = threadIdx.x;
    int n = (int)min(cntp[b * 64], (u32)CAP);
    u64* cb = cand + (size_t)b * CAP;
    for (int i = tid; i < CAP; i += 1024) keys[i] = (i < n) ? cb[i] : 0ULL;
    __syncthreads();
    for (int k = 2; k <= CAP; k <<= 1) {
        for (int j = k >> 1; j > 0; j >>= 1) {
            for (int i = tid; i < CAP; i += 1024) {
                int ixj = i ^ j;
                if (ixj > i) {
                    u64 x = keys[i], y = keys[ixj];
                    bool desc = ((i & k) == 0);
                    if (desc ? (x < y) : (x > y)) { keys[i] = y; keys[ixj] = x; }
                }
            }
            __syncthreads();
        }
    }
    for (int i = tid; i < PRE; i += 1024) cb[i] = keys[i];
}

// ---------------- decode+clip top-PRE boxes; prefill output --------------------
__global__ void decode_kernel(const u64* __restrict__ cand, const float* __restrict__ deltas,
                              const float* __restrict__ img_info, float4* __restrict__ boxes,
                              float* __restrict__ out) {
    int s = blockIdx.x * 256 + threadIdx.x;
    int b = blockIdx.y;
    if (s < POST) {
        float* o = out + ((size_t)b * POST + s) * 5;
        o[0] = (float)b; o[1] = 0.f; o[2] = 0.f; o[3] = 0.f; o[4] = 0.f;
    }
    if (s >= BOXSTRIDE) return;
    if (s >= PRE) { boxes[(size_t)b * BOXSTRIDE + s] = make_float4(0.f, 0.f, 0.f, 0.f); return; }

    u64 key = cand[(size_t)b * CAP + s];
    int a = (int)(~(u32)key);
    float a0, a1, a2, a3;
    anchor_at(a, a0, a1, a2, a3);
    const float4 d4 = *(const float4*)(deltas + ((size_t)b * NA + a) * 4);
    float hmax = __fsub_rn(img_info[b * 3 + 0], 1.0f);
    float wmax = __fsub_rn(img_info[b * 3 + 1], 1.0f);
    float w  = __fadd_rn(__fsub_rn(a2, a0), 1.0f);
    float h  = __fadd_rn(__fsub_rn(a3, a1), 1.0f);
    float cx = __fadd_rn(a0, __fmul_rn(0.5f, w));
    float cy = __fadd_rn(a1, __fmul_rn(0.5f, h));
    float pcx = __fadd_rn(__fmul_rn(d4.x, w), cx);
    float pcy = __fadd_rn(__fmul_rn(d4.y, h), cy);
    float pw  = __fmul_rn((float)exp((double)d4.z), w);
    float ph  = __fmul_rn((float)exp((double)d4.w), h);
    float x1 = __fsub_rn(pcx, __fmul_rn(0.5f, pw));
    float y1 = __fsub_rn(pcy, __fmul_rn(0.5f, ph));
    float x2 = __fadd_rn(pcx, __fmul_rn(0.5f, pw));
    float y2 = __fadd_rn(pcy, __fmul_rn(0.5f, ph));
    x1 = fminf(fmaxf(x1, 0.f), wmax);
    x2 = fminf(fmaxf(x2, 0.f), wmax);
    y1 = fminf(fmaxf(y1, 0.f), hmax);
    y2 = fminf(fmaxf(y2, 0.f), hmax);
    boxes[(size_t)b * BOXSTRIDE + s] = make_float4(x1, y1, x2, y2);
}

// ---------------- IoU suppression bit-mask build (column-per-lane) -------------
// mask[b][i][W] bit k: suppression of col 32W+k by row i. Each wave owns a
// 64-column strip (cols in registers); row boxes broadcast from LDS (uniform
// address -> conflict-free). One __ballot per (row, 64 cols) yields 2 words.
__global__ __launch_bounds__(256) void mask_kernel(const float4* __restrict__ boxes,
                                                   u32* __restrict__ mask) {
    __shared__ float4 rowbox[64];
    __shared__ float  rowarea[64];
    int rt = blockIdx.x;          // 94 row tiles of 64 rows
    int b  = blockIdx.y;
    int t  = threadIdx.x;
    int r0 = rt * 64;
    const float4* bb = boxes + (size_t)b * BOXSTRIDE;
    if (t < 64) {
        float4 rb = bb[r0 + t];
        rowbox[t] = rb;
        rowarea[t] = __fmul_rn(__fadd_rn(__fsub_rn(rb.z, rb.x), 1.0f),
                               __fadd_rn(__fsub_rn(rb.w, rb.y), 1.0f));
    }
    __syncthreads();

    int wave = t >> 6;            // 0..3
    int lane = t & 63;
    u32* mb = mask + (size_t)b * MROWS * ROWW;

    for (int cb = r0 + wave * 64; cb < MROWS; cb += 256) {
        float4 cbx = bb[cb + lane];
        float  ca  = __fmul_rn(__fadd_rn(__fsub_rn(cbx.z, cbx.x), 1.0f),
                               __fadd_rn(__fsub_rn(cbx.w, cbx.y), 1.0f));
        u32 keep0 = 0, keep1 = 0;
        #pragma unroll 4
        for (int r = 0; r < 64; ++r) {
            float4 rb = rowbox[r];
            float  ra = rowarea[r];
            float xx1 = fmaxf(cbx.x, rb.x);
            float yy1 = fmaxf(cbx.y, rb.y);
            float xx2 = fminf(cbx.z, rb.z);
            float yy2 = fminf(cbx.w, rb.w);
            float iw = fmaxf(__fadd_rn(__fsub_rn(xx2, xx1), 1.0f), 0.f);
            float ih = fmaxf(__fadd_rn(__fsub_rn(yy2, yy1), 1.0f), 0.f);
            float inter = __fmul_rn(iw, ih);
            float denom = __fsub_rn(__fadd_rn(ca, ra), inter);
            bool supp = ((double)inter >= MBOUND * (double)denom);
            u64 bal = __ballot(supp);
            if (lane == r) { keep0 = (u32)bal; keep1 = (u32)(bal >> 32); }
        }
        int row = r0 + lane;
        int W = cb >> 5;
        mb[(size_t)row * ROWW + W]     = keep0;
        mb[(size_t)row * ROWW + W + 1] = keep1;
    }
}

// ---------------- streaming greedy NMS scan (one wave per batch) ---------------
// Index-order row stream with a 32-deep register prefetch ring; aliveness via
// __ballot; suppression gated per-word by (w0 >= word(i)).
__global__ __launch_bounds__(64) void scan_kernel(const u32* __restrict__ mask,
                                                  const float4* __restrict__ boxes,
                                                  float* __restrict__ out) {
    __shared__ int keepIdx[POST];
    int b = blockIdx.x, l = threadIdx.x;
    int w0 = 3 * l;
    u32 aw0 = (w0     < 187) ? 0xFFFFFFFFu : ((w0     == 187) ? 0xFFFFu : 0u);
    u32 aw1 = (w0 + 1 < 187) ? 0xFFFFFFFFu : ((w0 + 1 == 187) ? 0xFFFFu : 0u);
    u32 aw2 = (w0 + 2 < 187) ? 0xFFFFFFFFu : ((w0 + 2 == 187) ? 0xFFFFu : 0u);
    const u32* mb = mask + (size_t)b * MROWS * ROWW + w0;

    u32 pf[32][3];
    #pragma unroll
    for (int u = 0; u < 32; ++u) {
        const u32* r = mb + (size_t)u * ROWW;
        pf[u][0] = r[0]; pf[u][1] = r[1]; pf[u][2] = r[2];
    }

    int kept = 0;
    for (int ib = 0; ib < PRE; ib += 32) {
        #pragma unroll
        for (int u = 0; u < 32; ++u) {
            int i = ib + u;
            int w = i >> 5;
            int bit = i & 31;
            int ol = w / 3;
            int q  = w - 3 * ol;
            u32 myw = (q == 0) ? aw0 : ((q == 1) ? aw1 : aw2);
            bool pred = (l == ol) && ((myw >> bit) & 1u);
            u32 r0 = pf[u][0], r1 = pf[u][1], r2 = pf[u][2];
            int pr = i + 32;                    // prefetch row (clamped in-bounds)
            if (pr > MROWS - 1) pr = MROWS - 1;
            const u32* rp = mb + (size_t)pr * ROWW;
            pf[u][0] = rp[0]; pf[u][1] = rp[1]; pf[u][2] = rp[2];
            if (__ballot(pred)) {
                if (pred) keepIdx[kept] = i;
                aw0 &= ~((w0     >= w) ? r0 : 0u);
                aw1 &= ~((w0 + 1 >= w) ? r1 : 0u);
                aw2 &= ~((w0 + 2 >= w) ? r2 : 0u);
                ++kept;
                if (kept == POST) goto scan_done;
            }
        }
    }
scan_done:
    __syncthreads();
    for (int s = l; s < kept; s += 64) {
        int j = keepIdx[s];
        float4 bx = boxes[(size_t)b * BOXSTRIDE + j];
        float* o = out + ((size_t)b * POST + s) * 5;
        o[0] = (float)b; o[1] = bx.x; o[2] = bx.y; o[3] = bx.z; o[4] = bx.w;
    }
}

// ---------------- fallback: monolithic sort+decode+NMS (small ws) --------------
__global__ __launch_bounds__(1024) void final_kernel(const u64* __restrict__ cand, const u32* __restrict__ cntp,
                             const float* __restrict__ deltas, const float* __restrict__ img_info,
                             float* __restrict__ out) {
    __shared__ union {
        u64 keys[CAP];
        struct {
            float boxes[PRE][4];
            float areas[PRE];
            u32   alive[192];
        } n;
    } sh;
    __shared__ int s_next;

    int b = blockIdx.x;
    int tid = threadIdx.x;

    for (int s = tid; s < POST; s += 1024) {
        float* o = out + ((size_t)b * POST + s) * 5;
        o[0] = (float)b; o[1] = 0.f; o[2] = 0.f; o[3] = 0.f; o[4] = 0.f;
    }

    int n = (int)min(cntp[b * 64], (u32)CAP);
    for (int i = tid; i < CAP; i += 1024)
        sh.keys[i] = (i < n) ? cand[(size_t)b * CAP + i] : 0ULL;
    __syncthreads();

    for (int k = 2; k <= CAP; k <<= 1) {
        for (int j = k >> 1; j > 0; j >>= 1) {
            for (int i = tid; i < CAP; i += 1024) {
                int ixj = i ^ j;
                if (ixj > i) {
                    u64 x = sh.keys[i], y = sh.keys[ixj];
                    bool desc = ((i & k) == 0);
                    if (desc ? (x < y) : (x > y)) { sh.keys[i] = y; sh.keys[ixj] = x; }
                }
            }
            __syncthreads();
        }
    }

    u32 myIdx[6];
    #pragma unroll
    for (int r = 0; r < 6; r++) {
        int i = tid + r * 1024;
        if (i < PRE) myIdx[r] = ~(u32)(sh.keys[i]);
    }
    __syncthreads();

    float hmax = __fsub_rn(img_info[b * 3 + 0], 1.0f);
    float wmax = __fsub_rn(img_info[b * 3 + 1], 1.0f);

    #pragma unroll
    for (int r = 0; r < 6; r++) {
        int i = tid + r * 1024;
        if (i < PRE) {
            int a = (int)myIdx[r];
            float a0, a1, a2, a3;
            anchor_at(a, a0, a1, a2, a3);
            const float4 d4 = *(const float4*)(deltas + ((size_t)b * NA + a) * 4);
            float w  = __fadd_rn(__fsub_rn(a2, a0), 1.0f);
            float h  = __fadd_rn(__fsub_rn(a3, a1), 1.0f);
            float cx = __fadd_rn(a0, __fmul_rn(0.5f, w));
            float cy = __fadd_rn(a1, __fmul_rn(0.5f, h));
            float pcx = __fadd_rn(__fmul_rn(d4.x, w), cx);
            float pcy = __fadd_rn(__fmul_rn(d4.y, h), cy);
            float pw  = __fmul_rn((float)exp((double)d4.z), w);
            float ph  = __fmul_rn((float)exp((double)d4.w), h);
            float x1 = __fsub_rn(pcx, __fmul_rn(0.5f, pw));
            float y1 = __fsub_rn(pcy, __fmul_rn(0.5f, ph));
            float x2 = __fadd_rn(pcx, __fmul_rn(0.5f, pw));
            float y2 = __fadd_rn(pcy, __fmul_rn(0.5f, ph));
            x1 = fminf(fmaxf(x1, 0.f), wmax);
            x2 = fminf(fmaxf(x2, 0.f), wmax);
            y1 = fminf(fmaxf(y1, 0.f), hmax);
            y2 = fminf(fmaxf(y2, 0.f), hmax);
            sh.n.boxes[i][0] = x1; sh.n.boxes[i][1] = y1;
            sh.n.boxes[i][2] = x2; sh.n.boxes[i][3] = y2;
            sh.n.areas[i] = __fmul_rn(__fadd_rn(__fsub_rn(x2, x1), 1.0f),
                                      __fadd_rn(__fsub_rn(y2, y1), 1.0f));
        }
    }

    for (int wdi = tid; wdi < 192; wdi += 1024) {
        u32 v = 0xFFFFFFFFu;
        if (wdi == 187) v = 0x0000FFFFu;
        if (wdi > 187)  v = 0u;
        sh.n.alive[wdi] = v;
    }
    __syncthreads();

    int kept = 0;
    int scanWord = 0;
    while (kept < POST) {
        if (tid == 0) {
            int found = -1;
            while (scanWord < 188) {
                u32 wv = sh.n.alive[scanWord];
                if (wv) { found = scanWord * 32 + (__ffs(wv) - 1); break; }
                scanWord++;
            }
            s_next = found;
        }
        __syncthreads();
        int i = s_next;
        if (i < 0) break;
        float bx1 = sh.n.boxes[i][0], by1 = sh.n.boxes[i][1];
        float bx2 = sh.n.boxes[i][2], by2 = sh.n.boxes[i][3];
        float bar = sh.n.areas[i];
        if (tid == 0) {
            float* o = out + ((size_t)b * POST + kept) * 5;
            o[1] = bx1; o[2] = by1; o[3] = bx2; o[4] = by2;
            atomicAnd(&sh.n.alive[i >> 5], ~(1u << (i & 31)));
        }
        for (int j = i + 1 + tid; j < PRE; j += 1024) {
            float x1 = sh.n.boxes[j][0], y1 = sh.n.boxes[j][1];
            float x2 = sh.n.boxes[j][2], y2 = sh.n.boxes[j][3];
            float xx1 = fmaxf(x1, bx1), yy1 = fmaxf(y1, by1);
            float xx2 = fminf(x2, bx2), yy2 = fminf(y2, by2);
            float iw = fmaxf(__fadd_rn(__fsub_rn(xx2, xx1), 1.0f), 0.f);
            float ih = fmaxf(__fadd_rn(__fsub_rn(yy2, yy1), 1.0f), 0.f);
            float inter = __fmul_rn(iw, ih);
            float denom = __fsub_rn(__fadd_rn(sh.n.areas[j], bar), inter);
            float iou = __fdiv_rn(inter, denom);
            if (iou > 0.7f) atomicAnd(&sh.n.alive[j >> 5], ~(1u << (j & 31)));
        }
        kept++;
        __syncthreads();
    }
}

// ---------------- launcher -----------------------------------------------------
extern "C" void kernel_launch(void* const* d_in, const int* in_sizes, int n_in,
                              void* d_out, int out_size, void* d_ws, size_t ws_size,
                              hipStream_t stream) {
    const float* probs    = (const float*)d_in[0];
    const float* deltas   = (const float*)d_in[1];
    const float* img_info = (const float*)d_in[2];
    float* out = (float*)d_out;

    char* ws = (char*)d_ws;
    size_t off = 0;
    u32* cntp = (u32*)(ws + off); off += (size_t)NB * 64 * sizeof(u32);      // 4 KiB, 256B-strided counters
    u32* flag = (u32*)(ws + off); off += (size_t)NB * 64 * sizeof(u32);      // 4 KiB
    u32* thr  = (u32*)(ws + off); off += 4096;                                // 16 u32 (padded)
    u32* hist = (u32*)(ws + off); off += (size_t)NB * 65536 * sizeof(u32);   // 4 MiB
    u64* cand = (u64*)(ws + off); off += (size_t)NB * CAP * sizeof(u64);     // 1 MiB
    float4* boxes = (float4*)(ws + off); off += (size_t)NB * BOXSTRIDE * sizeof(float4); // 1.5 MiB
    u32* mask = (u32*)(ws + off); off += (size_t)NB * MROWS * ROWW * sizeof(u32);        // 73.9 MiB
    bool bigws = (ws_size >= off);

    dim3 gA((NA + 255) / 256, NB);

    hipMemsetAsync(cntp, 0, (size_t)NB * 64 * sizeof(u32), stream);

    if (bigws) {
        compact_fixed<<<gA, 256, 0, stream>>>(probs, cntp, cand);
        check_kernel<<<1, 64, 0, stream>>>(cntp, flag);
        // gated exact fallback (no-ops when all flags clean)
        zero_hist<<<dim3(256, NB), 256, 0, stream>>>(flag, hist);
        hist_kernel<<<gA, 256, 0, stream>>>(flag, probs, hist);
        thresh_kernel<<<NB, 1024, 0, stream>>>(flag, hist, thr);
        compact2_kernel<<<gA, 256, 0, stream>>>(flag, probs, thr, cntp, cand);
        // main pipeline
        sort_kernel<<<NB, 1024, 0, stream>>>(cand, cntp);
        decode_kernel<<<dim3(BOXSTRIDE / 256, NB), 256, 0, stream>>>(cand, deltas, img_info, boxes, out);
        mask_kernel<<<dim3(94, NB), 256, 0, stream>>>(boxes, mask);
        scan_kernel<<<NB, 64, 0, stream>>>(mask, boxes, out);
    } else {
        // small-ws: force fallback flags on, run exact path + monolithic NMS
        hipMemsetAsync(flag, 1, (size_t)NB * 64 * sizeof(u32), stream);   // nonzero == run
        hipMemsetAsync(hist, 0, (size_t)NB * 65536 * sizeof(u32), stream);
        hist_kernel<<<gA, 256, 0, stream>>>(flag, probs, hist);
        thresh_kernel<<<NB, 1024, 0, stream>>>(flag, hist, thr);
        compact2_kernel<<<gA, 256, 0, stream>>>(flag, probs, thr, cntp, cand);
        final_kernel<<<NB, 1024, 0, stream>>>(cand, cntp, deltas, img_info, out);
    }
}